// Round 1
// baseline (2593.941 us; speedup 1.0000x reference)
//
#include <hip/hip_runtime.h>
#include <cstddef>

#define B_SZ 256
#define L_SZ 1026
#define D_SZ 1280
#define E_SZ 300
#define H_SZ 256
#define SPLIT 4

// ---------------- pooling ----------------
// grid (B, SPLIT), block 320. Each thread owns one float4 lane of D (1280/4=320).
__global__ void pool_partial_kernel(const float* __restrict__ reps,
                                    const int* __restrict__ lens,
                                    float* __restrict__ part) {
  int b = blockIdx.x, s = blockIdx.y, t = threadIdx.x;
  int n = lens[b] - 2;
  if (n < 0) n = 0;
  int start = 1 + (n * s) / SPLIT;
  int end   = 1 + (n * (s + 1)) / SPLIT;
  const float4* base = (const float4*)reps + (size_t)b * L_SZ * (D_SZ / 4);
  float ax = 0.f, ay = 0.f, az = 0.f, aw = 0.f;
  for (int l = start; l < end; ++l) {
    float4 v = base[(size_t)l * (D_SZ / 4) + t];
    ax += v.x; ay += v.y; az += v.z; aw += v.w;
  }
  float4* p = (float4*)part + ((size_t)s * B_SZ + b) * (D_SZ / 4);
  p[t] = make_float4(ax, ay, az, aw);
}

// grid B, block 320: sum SPLIT partials, divide by count.
__global__ void pool_reduce_kernel(const float* __restrict__ part,
                                   const int* __restrict__ lens,
                                   float* __restrict__ pooled) {
  int b = blockIdx.x, t = threadIdx.x;
  const float4* p4 = (const float4*)part;
  float4 a = make_float4(0.f, 0.f, 0.f, 0.f);
  #pragma unroll
  for (int s = 0; s < SPLIT; ++s) {
    float4 v = p4[((size_t)s * B_SZ + b) * (D_SZ / 4) + t];
    a.x += v.x; a.y += v.y; a.z += v.z; a.w += v.w;
  }
  int n = lens[b] - 2;
  float inv = 1.f / (float)(n < 1 ? 1 : n);
  a.x *= inv; a.y *= inv; a.z *= inv; a.w *= inv;
  ((float4*)pooled)[(size_t)b * (D_SZ / 4) + t] = a;
}

// ---------------- generic fp32 tiled GEMM ----------------
// C[M,N] = op_A(A) @ op_B(B) (+bias[n]) (relu).
// TA: A stored [K,M] (read A[k*M+m]); else [M,K].
// TB: B stored [N,K] (read B[n*K+k]); else [K,N].
template <bool TA, bool TB, bool RELU>
__global__ void gemm_kernel(const float* __restrict__ A, const float* __restrict__ Bm,
                            const float* __restrict__ bias, float* __restrict__ C,
                            int M, int N, int K) {
  __shared__ float As[16][65];
  __shared__ float Bs[16][65];
  int bm = blockIdx.y * 64, bn = blockIdx.x * 64;
  int tid = threadIdx.x;
  int tx = tid & 15, ty = tid >> 4;
  float acc[4][4] = {};
  for (int k0 = 0; k0 < K; k0 += 16) {
    if (!TA) {
      int kk = tid & 15, mr = tid >> 4;
      #pragma unroll
      for (int i = 0; i < 4; ++i) {
        int m = mr * 4 + i;
        int gm = bm + m, gk = k0 + kk;
        As[kk][m] = (gm < M && gk < K) ? A[(size_t)gm * K + gk] : 0.f;
      }
    } else {
      int ml = tid & 63, kr = tid >> 6;
      #pragma unroll
      for (int i = 0; i < 4; ++i) {
        int k = kr * 4 + i;
        int gm = bm + ml, gk = k0 + k;
        As[k][ml] = (gm < M && gk < K) ? A[(size_t)gk * M + gm] : 0.f;
      }
    }
    if (!TB) {
      int nl = tid & 63, kr = tid >> 6;
      #pragma unroll
      for (int i = 0; i < 4; ++i) {
        int k = kr * 4 + i;
        int gn = bn + nl, gk = k0 + k;
        Bs[k][nl] = (gn < N && gk < K) ? Bm[(size_t)gk * N + gn] : 0.f;
      }
    } else {
      int kk = tid & 15, nr = tid >> 4;
      #pragma unroll
      for (int i = 0; i < 4; ++i) {
        int nn = nr * 4 + i;
        int gn = bn + nn, gk = k0 + kk;
        Bs[kk][nn] = (gn < N && gk < K) ? Bm[(size_t)gn * K + gk] : 0.f;
      }
    }
    __syncthreads();
    #pragma unroll
    for (int kk = 0; kk < 16; ++kk) {
      float a0 = As[kk][ty * 4 + 0], a1 = As[kk][ty * 4 + 1];
      float a2 = As[kk][ty * 4 + 2], a3 = As[kk][ty * 4 + 3];
      float b0 = Bs[kk][tx * 4 + 0], b1 = Bs[kk][tx * 4 + 1];
      float b2 = Bs[kk][tx * 4 + 2], b3 = Bs[kk][tx * 4 + 3];
      acc[0][0] += a0 * b0; acc[0][1] += a0 * b1; acc[0][2] += a0 * b2; acc[0][3] += a0 * b3;
      acc[1][0] += a1 * b0; acc[1][1] += a1 * b1; acc[1][2] += a1 * b2; acc[1][3] += a1 * b3;
      acc[2][0] += a2 * b0; acc[2][1] += a2 * b1; acc[2][2] += a2 * b2; acc[2][3] += a2 * b3;
      acc[3][0] += a3 * b0; acc[3][1] += a3 * b1; acc[3][2] += a3 * b2; acc[3][3] += a3 * b3;
    }
    __syncthreads();
  }
  #pragma unroll
  for (int i = 0; i < 4; ++i) {
    int gm = bm + ty * 4 + i;
    if (gm >= M) continue;
    #pragma unroll
    for (int j = 0; j < 4; ++j) {
      int gn = bn + tx * 4 + j;
      if (gn >= N) continue;
      float v = acc[i][j];
      if (bias) v += bias[gn];
      if (RELU) v = fmaxf(v, 0.f);
      C[(size_t)gm * N + gn] = v;
    }
  }
}

// ---------------- row softmax (in place), grid = rows, block 256 ----------------
__global__ void softmax_kernel(float* __restrict__ X, int N) {
  int r = blockIdx.x, tid = threadIdx.x;
  __shared__ float red[256];
  float* row = X + (size_t)r * N;
  float lmax = -1e30f;
  for (int j = tid; j < N; j += 256) lmax = fmaxf(lmax, row[j]);
  red[tid] = lmax;
  __syncthreads();
  for (int s = 128; s > 0; s >>= 1) {
    if (tid < s) red[tid] = fmaxf(red[tid], red[tid + s]);
    __syncthreads();
  }
  float m = red[0];
  __syncthreads();
  float lsum = 0.f;
  for (int j = tid; j < N; j += 256) {
    float e = __expf(row[j] - m);
    row[j] = e;
    lsum += e;
  }
  red[tid] = lsum;
  __syncthreads();
  for (int s = 128; s > 0; s >>= 1) {
    if (tid < s) red[tid] += red[tid + s];
    __syncthreads();
  }
  float inv = 1.f / red[0];
  for (int j = tid; j < N; j += 256) row[j] *= inv;
}

// ---------------- build combined = [x1*fx2+x1 , x2*fx1+x2] ----------------
__global__ void combine_kernel(const float* __restrict__ x1, const float* __restrict__ fx2,
                               const float* __restrict__ x2, const float* __restrict__ fx1,
                               float* __restrict__ comb) {
  int b = blockIdx.x, tid = threadIdx.x;
  float* crow = comb + (size_t)b * (D_SZ + E_SZ);
  const float* x1r = x1 + (size_t)b * D_SZ;
  const float* f2r = fx2 + (size_t)b * D_SZ;
  const float* x2r = x2 + (size_t)b * E_SZ;
  const float* f1r = fx1 + (size_t)b * E_SZ;
  for (int j = tid; j < D_SZ; j += 256) {
    float v = x1r[j];
    crow[j] = v * f2r[j] + v;
  }
  for (int j = tid; j < E_SZ; j += 256) {
    float v = x2r[j];
    crow[D_SZ + j] = v * f1r[j] + v;
  }
}

// ---------------- final: out[b] = dot(h[b,:], W_fc2) + b_fc2 ----------------
__global__ void fc2_kernel(const float* __restrict__ h, const float* __restrict__ W2,
                           const float* __restrict__ b2, float* __restrict__ out) {
  int b = blockIdx.x, lane = threadIdx.x;  // 64 threads
  float s = 0.f;
  for (int j = lane; j < H_SZ; j += 64) s += h[(size_t)b * H_SZ + j] * W2[j];
  for (int off = 32; off > 0; off >>= 1) s += __shfl_down(s, off);
  if (lane == 0) out[b] = s + b2[0];
}

extern "C" void kernel_launch(void* const* d_in, const int* in_sizes, int n_in,
                              void* d_out, int out_size, void* d_ws, size_t ws_size,
                              hipStream_t stream) {
  const float* token_reps = (const float*)d_in[0];
  const int*   batch_lens = (const int*)d_in[1];
  const float* mol        = (const float*)d_in[2];
  const float* W_prot     = (const float*)d_in[3];
  const float* b_prot     = (const float*)d_in[4];
  const float* W_attn     = (const float*)d_in[5];
  const float* b_attn     = (const float*)d_in[6];
  const float* W_fc1      = (const float*)d_in[7];
  const float* b_fc1      = (const float*)d_in[8];
  const float* W_fc2      = (const float*)d_in[9];
  const float* b_fc2      = (const float*)d_in[10];
  float* out = (float*)d_out;

  float* ws     = (float*)d_ws;
  float* part   = ws;                                  // SPLIT*B*D
  float* pooled = part + (size_t)SPLIT * B_SZ * D_SZ;  // B*D
  float* x1     = pooled + (size_t)B_SZ * D_SZ;        // B*D
  float* Aattn  = x1 + (size_t)B_SZ * D_SZ;            // B*E
  float* attn   = Aattn + (size_t)B_SZ * E_SZ;         // B*B
  float* T1     = attn + (size_t)B_SZ * B_SZ;          // B*E (fused_x1)
  float* T2     = T1 + (size_t)B_SZ * E_SZ;            // B*D (fused_x2)
  float* comb   = T2 + (size_t)B_SZ * D_SZ;            // B*(D+E)
  float* h      = comb + (size_t)B_SZ * (D_SZ + E_SZ); // B*H

  // 1. ragged mean pool
  pool_partial_kernel<<<dim3(B_SZ, SPLIT), 320, 0, stream>>>(token_reps, batch_lens, part);
  pool_reduce_kernel<<<B_SZ, 320, 0, stream>>>(part, batch_lens, pooled);

  // 2. x1 = relu(pooled @ W_prot + b_prot)   [256,1280]
  gemm_kernel<false, false, true><<<dim3(20, 4), 256, 0, stream>>>(
      pooled, W_prot, b_prot, x1, B_SZ, D_SZ, D_SZ);

  // 3. Aattn = x1 @ W_attn + b_attn          [256,300]
  gemm_kernel<false, false, false><<<dim3(5, 4), 256, 0, stream>>>(
      x1, W_attn, b_attn, Aattn, B_SZ, E_SZ, D_SZ);

  // 4. attn = softmax(Aattn @ mol^T)         [256,256]
  gemm_kernel<false, true, false><<<dim3(4, 4), 256, 0, stream>>>(
      Aattn, mol, nullptr, attn, B_SZ, B_SZ, E_SZ);
  softmax_kernel<<<B_SZ, 256, 0, stream>>>(attn, B_SZ);

  // 5. fused_x1 = softmax(attn @ mol)        [256,300]
  gemm_kernel<false, false, false><<<dim3(5, 4), 256, 0, stream>>>(
      attn, mol, nullptr, T1, B_SZ, E_SZ, B_SZ);
  softmax_kernel<<<B_SZ, 256, 0, stream>>>(T1, E_SZ);

  // 6. fused_x2 = softmax(attn^T @ x1)       [256,1280]
  gemm_kernel<true, false, false><<<dim3(20, 4), 256, 0, stream>>>(
      attn, x1, nullptr, T2, B_SZ, D_SZ, B_SZ);
  softmax_kernel<<<B_SZ, 256, 0, stream>>>(T2, D_SZ);

  // 7. combined
  combine_kernel<<<B_SZ, 256, 0, stream>>>(x1, T2, mol, T1, comb);

  // 8. h = relu(combined @ W_fc1 + b_fc1)    [256,256]
  gemm_kernel<false, false, true><<<dim3(4, 4), 256, 0, stream>>>(
      comb, W_fc1, b_fc1, h, B_SZ, H_SZ, D_SZ + E_SZ);

  // 9. out = h @ W_fc2 + b_fc2               [256,1]
  fc2_kernel<<<B_SZ, 64, 0, stream>>>(h, W_fc2, b_fc2, out);
}